// Round 1
// baseline (773.477 us; speedup 1.0000x reference)
//
#include <hip/hip_runtime.h>
#include <hip/hip_bf16.h>

#define CH 64

// ---------------------------------------------------------------------------
// Kernel 1: fused dual GEMM.  xw = x @ w_conv  (to workspace)
//                             acc = x @ w_lin  (to d_out, pre-activation acc)
// Weights staged in LDS; x row broadcast across the 64-lane wave via __shfl.
// ---------------------------------------------------------------------------
__global__ __launch_bounds__(256) void gemm2_kernel(
    const float* __restrict__ x,
    const float* __restrict__ wc,
    const float* __restrict__ wl,
    float* __restrict__ xw,
    float* __restrict__ acc,
    int n) {
  __shared__ float swc[CH * CH];
  __shared__ float swl[CH * CH];
  for (int i = threadIdx.x; i < CH * CH; i += 256) {
    swc[i] = wc[i];
    swl[i] = wl[i];
  }
  __syncthreads();

  const int lane = threadIdx.x & 63;
  const int wrow = threadIdx.x >> 6;  // wave id in block: 0..3

  for (int row = blockIdx.x * 4 + wrow; row < n; row += gridDim.x * 4) {
    const float xv = x[row * CH + lane];
    float a1 = 0.f, a2 = 0.f;
#pragma unroll
    for (int k = 0; k < CH; ++k) {
      const float xk = __shfl(xv, k, 64);
      a1 = fmaf(xk, swc[k * CH + lane], a1);
      a2 = fmaf(xk, swl[k * CH + lane], a2);
    }
    xw[row * CH + lane] = a1;
    acc[row * CH + lane] = a2;
  }
}

// ---------------------------------------------------------------------------
// Kernel 2: sparse scatter-add.  For each nnz k:
//   out[rows[k]][c] += vals[k] * xw[cols[k]][c]   (c = lane, 64 channels)
// One 64-lane wave per nnz, grid-stride over nnz.
// ---------------------------------------------------------------------------
__global__ __launch_bounds__(256) void scatter_kernel(
    const int* __restrict__ rows,
    const int* __restrict__ cols,
    const float* __restrict__ vals,
    const float* __restrict__ xw,
    float* __restrict__ out,
    int nnz) {
  const int lane = threadIdx.x & 63;
  const int wid = (blockIdx.x * blockDim.x + threadIdx.x) >> 6;
  const int nwaves = (gridDim.x * blockDim.x) >> 6;

  for (int k = wid; k < nnz; k += nwaves) {
    const int r = rows[k];
    const int c = cols[k];
    const float v = vals[k];
    const float xv = xw[c * CH + lane];
    atomicAdd(&out[r * CH + lane], v * xv);
  }
}

// ---------------------------------------------------------------------------
// Kernel 3: in-place sigmoid, float4 vectorized.
// ---------------------------------------------------------------------------
__global__ __launch_bounds__(256) void sigmoid_kernel(float* __restrict__ out, int n4) {
  int i = blockIdx.x * blockDim.x + threadIdx.x;
  if (i < n4) {
    float4 v = reinterpret_cast<float4*>(out)[i];
    v.x = 1.f / (1.f + __expf(-v.x));
    v.y = 1.f / (1.f + __expf(-v.y));
    v.z = 1.f / (1.f + __expf(-v.z));
    v.w = 1.f / (1.f + __expf(-v.w));
    reinterpret_cast<float4*>(out)[i] = v;
  }
}

extern "C" void kernel_launch(void* const* d_in, const int* in_sizes, int n_in,
                              void* d_out, int out_size, void* d_ws, size_t ws_size,
                              hipStream_t stream) {
  const float* x         = (const float*)d_in[0];
  const int*   down_rows = (const int*)d_in[1];
  const int*   down_cols = (const int*)d_in[2];
  const float* down_vals = (const float*)d_in[3];
  const int*   up_rows   = (const int*)d_in[4];
  const int*   up_cols   = (const int*)d_in[5];
  const float* up_vals   = (const float*)d_in[6];
  const float* w_conv    = (const float*)d_in[7];
  const float* w_lin     = (const float*)d_in[8];

  const int n   = in_sizes[0] / CH;   // 100000
  const int nnz = in_sizes[1];        // 1600000

  float* out = (float*)d_out;
  float* xw  = (float*)d_ws;          // n*CH floats = 25.6 MB scratch

  // 1) xw = x@w_conv (ws), out = x@w_lin (accumulator init)
  gemm2_kernel<<<4096, 256, 0, stream>>>(x, w_conv, w_lin, xw, out, n);

  // 2) out += L_down @ xw ; out += L_up @ xw
  scatter_kernel<<<4096, 256, 0, stream>>>(down_rows, down_cols, down_vals, xw, out, nnz);
  scatter_kernel<<<4096, 256, 0, stream>>>(up_rows, up_cols, up_vals, xw, out, nnz);

  // 3) sigmoid in place
  const int n4 = (n * CH) / 4;
  sigmoid_kernel<<<(n4 + 255) / 256, 256, 0, stream>>>(out, n4);
}

// Round 2
// 604.435 us; speedup vs baseline: 1.2797x; 1.2797x over previous
//
#include <hip/hip_runtime.h>
#include <hip/hip_bf16.h>

#define CH 64
#define SCAN_B 256

// ---------------------------------------------------------------------------
// Kernel 1: fused dual GEMM.  xw = x @ w_conv  (to workspace)
//                             acc = x @ w_lin  (to d_out, pre-activation acc)
// ---------------------------------------------------------------------------
__global__ __launch_bounds__(256) void gemm2_kernel(
    const float* __restrict__ x,
    const float* __restrict__ wc,
    const float* __restrict__ wl,
    float* __restrict__ xw,
    float* __restrict__ acc,
    int n) {
  __shared__ float swc[CH * CH];
  __shared__ float swl[CH * CH];
  for (int i = threadIdx.x; i < CH * CH; i += 256) {
    swc[i] = wc[i];
    swl[i] = wl[i];
  }
  __syncthreads();

  const int lane = threadIdx.x & 63;
  const int wrow = threadIdx.x >> 6;

  for (int row = blockIdx.x * 4 + wrow; row < n; row += gridDim.x * 4) {
    const float xv = x[row * CH + lane];
    float a1 = 0.f, a2 = 0.f;
#pragma unroll
    for (int k = 0; k < CH; ++k) {
      const float xk = __shfl(xv, k, 64);
      a1 = fmaf(xk, swc[k * CH + lane], a1);
      a2 = fmaf(xk, swl[k * CH + lane], a2);
    }
    xw[row * CH + lane] = a1;
    acc[row * CH + lane] = a2;
  }
}

// ---------------------------------------------------------------------------
// CSR construction: histogram -> scan -> fill
// ---------------------------------------------------------------------------
__global__ __launch_bounds__(256) void hist_kernel(
    const int* __restrict__ r1, const int* __restrict__ r2,
    int* __restrict__ cnt, int nnz) {
  const int tot = 2 * nnz;
  for (int i = blockIdx.x * blockDim.x + threadIdx.x; i < tot;
       i += gridDim.x * blockDim.x) {
    const int r = (i < nnz) ? r1[i] : r2[i - nnz];
    atomicAdd(&cnt[r], 1);
  }
}

__global__ __launch_bounds__(SCAN_B) void scan_partial(
    const int* __restrict__ cnt, int* __restrict__ partials, int n) {
  __shared__ int s[SCAN_B];
  const int i = blockIdx.x * SCAN_B + threadIdx.x;
  s[threadIdx.x] = (i < n) ? cnt[i] : 0;
  __syncthreads();
  for (int off = SCAN_B / 2; off > 0; off >>= 1) {
    if (threadIdx.x < off) s[threadIdx.x] += s[threadIdx.x + off];
    __syncthreads();
  }
  if (threadIdx.x == 0) partials[blockIdx.x] = s[0];
}

__global__ __launch_bounds__(1024) void scan_partials_scan(
    int* __restrict__ partials, int nb) {
  __shared__ int s[1024];
  const int v = (threadIdx.x < nb) ? partials[threadIdx.x] : 0;
  s[threadIdx.x] = v;
  __syncthreads();
  for (int off = 1; off < 1024; off <<= 1) {
    const int t = (threadIdx.x >= off) ? s[threadIdx.x - off] : 0;
    __syncthreads();
    s[threadIdx.x] += t;
    __syncthreads();
  }
  if (threadIdx.x < nb) partials[threadIdx.x] = s[threadIdx.x] - v;  // exclusive
}

__global__ __launch_bounds__(SCAN_B) void scan_final(
    const int* __restrict__ cnt, const int* __restrict__ partials,
    int* __restrict__ row_ptr, int* __restrict__ cursor, int n) {
  __shared__ int s[SCAN_B];
  const int i = blockIdx.x * SCAN_B + threadIdx.x;
  const int v = (i < n) ? cnt[i] : 0;
  s[threadIdx.x] = v;
  __syncthreads();
  for (int off = 1; off < SCAN_B; off <<= 1) {
    const int t = (threadIdx.x >= off) ? s[threadIdx.x - off] : 0;
    __syncthreads();
    s[threadIdx.x] += t;
    __syncthreads();
  }
  const int excl = s[threadIdx.x] - v + partials[blockIdx.x];
  if (i < n) {
    row_ptr[i] = excl;
    cursor[i] = excl;
    if (i == n - 1) row_ptr[n] = excl + v;
  }
}

__global__ __launch_bounds__(256) void fill_kernel(
    const int* __restrict__ rows, const int* __restrict__ cols,
    const float* __restrict__ vals, int* __restrict__ cursor,
    int* __restrict__ ecol, float* __restrict__ eval, int nnz) {
  for (int i = blockIdx.x * blockDim.x + threadIdx.x; i < nnz;
       i += gridDim.x * blockDim.x) {
    const int r = rows[i];
    const int pos = atomicAdd(&cursor[r], 1);
    ecol[pos] = cols[i];
    eval[pos] = vals[i];
  }
}

// ---------------------------------------------------------------------------
// Gather: one wave per output row; acc in registers; fused sigmoid.
// out[] already holds the x@w_lin term.
// ---------------------------------------------------------------------------
__global__ __launch_bounds__(256) void gather_kernel(
    const int* __restrict__ row_ptr, const int* __restrict__ ecol,
    const float* __restrict__ eval, const float* __restrict__ xw,
    float* __restrict__ out, int n) {
  const int lane = threadIdx.x & 63;
  const int w = (blockIdx.x * blockDim.x + threadIdx.x) >> 6;
  const int nw = (gridDim.x * blockDim.x) >> 6;
  for (int row = w; row < n; row += nw) {
    const int beg = row_ptr[row];
    const int end = row_ptr[row + 1];
    float acc = out[row * CH + lane];  // linear term
    int e = beg;
    for (; e + 4 <= end; e += 4) {
      const int c0 = ecol[e], c1 = ecol[e + 1], c2 = ecol[e + 2], c3 = ecol[e + 3];
      const float v0 = eval[e], v1 = eval[e + 1], v2 = eval[e + 2], v3 = eval[e + 3];
      const float x0 = xw[c0 * CH + lane];
      const float x1 = xw[c1 * CH + lane];
      const float x2 = xw[c2 * CH + lane];
      const float x3 = xw[c3 * CH + lane];
      acc = fmaf(v0, x0, acc);
      acc = fmaf(v1, x1, acc);
      acc = fmaf(v2, x2, acc);
      acc = fmaf(v3, x3, acc);
    }
    for (; e < end; ++e) acc = fmaf(eval[e], xw[ecol[e] * CH + lane], acc);
    out[row * CH + lane] = 1.f / (1.f + __expf(-acc));
  }
}

// ---------------------------------------------------------------------------
// Fallback path (ws too small): atomic scatter + sigmoid (round-1 scheme).
// ---------------------------------------------------------------------------
__global__ __launch_bounds__(256) void scatter_kernel(
    const int* __restrict__ rows, const int* __restrict__ cols,
    const float* __restrict__ vals, const float* __restrict__ xw,
    float* __restrict__ out, int nnz) {
  const int lane = threadIdx.x & 63;
  const int wid = (blockIdx.x * blockDim.x + threadIdx.x) >> 6;
  const int nwaves = (gridDim.x * blockDim.x) >> 6;
  for (int k = wid; k < nnz; k += nwaves) {
    const float xv = xw[cols[k] * CH + lane];
    atomicAdd(&out[rows[k] * CH + lane], vals[k] * xv);
  }
}

__global__ __launch_bounds__(256) void sigmoid_kernel(float* __restrict__ out, int n4) {
  const int i = blockIdx.x * blockDim.x + threadIdx.x;
  if (i < n4) {
    float4 v = reinterpret_cast<float4*>(out)[i];
    v.x = 1.f / (1.f + __expf(-v.x));
    v.y = 1.f / (1.f + __expf(-v.y));
    v.z = 1.f / (1.f + __expf(-v.z));
    v.w = 1.f / (1.f + __expf(-v.w));
    reinterpret_cast<float4*>(out)[i] = v;
  }
}

extern "C" void kernel_launch(void* const* d_in, const int* in_sizes, int n_in,
                              void* d_out, int out_size, void* d_ws, size_t ws_size,
                              hipStream_t stream) {
  const float* x         = (const float*)d_in[0];
  const int*   down_rows = (const int*)d_in[1];
  const int*   down_cols = (const int*)d_in[2];
  const float* down_vals = (const float*)d_in[3];
  const int*   up_rows   = (const int*)d_in[4];
  const int*   up_cols   = (const int*)d_in[5];
  const float* up_vals   = (const float*)d_in[6];
  const float* w_conv    = (const float*)d_in[7];
  const float* w_lin     = (const float*)d_in[8];

  const int n    = in_sizes[0] / CH;  // 100000
  const int nnz  = in_sizes[1];       // 1600000
  const int nnz2 = 2 * nnz;

  float* out = (float*)d_out;

  // ws layout
  float* xw      = (float*)d_ws;                 // n*CH
  int*   cnt     = (int*)(xw + (size_t)n * CH);  // n
  int*   row_ptr = cnt + n;                      // n+1
  int*   cursor  = row_ptr + n + 1;              // n
  int*   partial = cursor + n;                   // 4096
  int*   ecol    = partial + 4096;               // nnz2
  float* eval    = (float*)(ecol + nnz2);        // nnz2
  const size_t need =
      ((size_t)n * CH + 3 * (size_t)n + 1 + 4096 + 2 * (size_t)nnz2) * 4;

  // xw = x@w_conv (ws), out = x@w_lin (accumulator)
  gemm2_kernel<<<4096, 256, 0, stream>>>(x, w_conv, w_lin, xw, out, n);

  if (ws_size >= need) {
    // ---- CSR build ----
    hipMemsetAsync(cnt, 0, (size_t)n * 4, stream);
    hist_kernel<<<4096, 256, 0, stream>>>(down_rows, up_rows, cnt, nnz);
    const int nb = (n + SCAN_B - 1) / SCAN_B;  // 391
    scan_partial<<<nb, SCAN_B, 0, stream>>>(cnt, partial, n);
    scan_partials_scan<<<1, 1024, 0, stream>>>(partial, nb);
    scan_final<<<nb, SCAN_B, 0, stream>>>(cnt, partial, row_ptr, cursor, n);
    fill_kernel<<<4096, 256, 0, stream>>>(down_rows, down_cols, down_vals,
                                          cursor, ecol, eval, nnz);
    fill_kernel<<<4096, 256, 0, stream>>>(up_rows, up_cols, up_vals,
                                          cursor, ecol, eval, nnz);
    // ---- gather + fused sigmoid ----
    const int nblk = (n + 3) / 4;  // 4 waves (rows) per 256-thread block
    gather_kernel<<<nblk, 256, 0, stream>>>(row_ptr, ecol, eval, xw, out, n);
  } else {
    // fallback: atomic scatter
    scatter_kernel<<<4096, 256, 0, stream>>>(down_rows, down_cols, down_vals, xw, out, nnz);
    scatter_kernel<<<4096, 256, 0, stream>>>(up_rows, up_cols, up_vals, xw, out, nnz);
    const int n4 = (n * CH) / 4;
    sigmoid_kernel<<<(n4 + 255) / 256, 256, 0, stream>>>(out, n4);
  }
}